// Round 1
// baseline (16585.080 us; speedup 1.0000x reference)
//
#include <hip/hip_runtime.h>
#include <math.h>

#define N_NODES 100000
#define N_EDGES 3200000
#define NFEAT   1433
#define NHID    40
#define NCLASS  7
#define NCHUNK  391   // ceil(100000/256)
#define GTILE   45    // ceil(1433/32)

// ---------------- CSR build ----------------
__global__ __launch_bounds__(256) void k_hist(const int* __restrict__ dst, int* __restrict__ deg) {
    int e = blockIdx.x * 256 + threadIdx.x;
    if (e < N_EDGES) atomicAdd(&deg[dst[e]], 1);
}

__global__ __launch_bounds__(256) void k_scan1(const int* __restrict__ deg, int* __restrict__ csum) {
    __shared__ int s[256];
    int tid = threadIdx.x;
    int n = blockIdx.x * 256 + tid;
    int v = (n < N_NODES) ? deg[n] : 0;
    s[tid] = v; __syncthreads();
    for (int off = 128; off > 0; off >>= 1) {
        if (tid < off) s[tid] += s[tid + off];
        __syncthreads();
    }
    if (tid == 0) csum[blockIdx.x] = s[0];
}

__global__ __launch_bounds__(512) void k_scan2(int* __restrict__ csum) {
    __shared__ int s[512];
    int tid = threadIdx.x;
    int v = (tid < NCHUNK) ? csum[tid] : 0;
    s[tid] = v; __syncthreads();
    for (int off = 1; off < 512; off <<= 1) {
        int t = (tid >= off) ? s[tid - off] : 0;
        __syncthreads();
        s[tid] += t;
        __syncthreads();
    }
    if (tid < NCHUNK) csum[tid] = s[tid] - v;  // exclusive
}

__global__ __launch_bounds__(256) void k_scan3(const int* __restrict__ deg, const int* __restrict__ csum,
                                               int* __restrict__ row_ptr, int* __restrict__ cursor) {
    __shared__ int s[256];
    int tid = threadIdx.x;
    int n = blockIdx.x * 256 + tid;
    int v = (n < N_NODES) ? deg[n] : 0;
    s[tid] = v; __syncthreads();
    for (int off = 1; off < 256; off <<= 1) {
        int t = (tid >= off) ? s[tid - off] : 0;
        __syncthreads();
        s[tid] += t;
        __syncthreads();
    }
    int excl = s[tid] - v + csum[blockIdx.x];
    if (n < N_NODES) { row_ptr[n] = excl; cursor[n] = excl; }
    if (n == 0) row_ptr[N_NODES] = N_EDGES;
}

__global__ __launch_bounds__(256) void k_scatter(const int* __restrict__ src, const int* __restrict__ dst,
                                                 const float* __restrict__ ew, int* __restrict__ cursor,
                                                 int2* __restrict__ csr) {
    int e = blockIdx.x * 256 + threadIdx.x;
    if (e < N_EDGES) {
        int d = dst[e];
        int pos = atomicAdd(&cursor[d], 1);
        int2 p; p.x = src[e]; p.y = __float_as_int(ew[e]);
        csr[pos] = p;
    }
}

// ---------------- GEMM1: sup1[N,40] = x[N,1433] @ W1[1433,40] ----------------
// Software-pipelined: reg-staged global loads (tile t+2 in flight across a
// NON-draining barrier) + double-buffered LDS. The barrier waits lgkmcnt(0)
// only — global loads stay outstanding and their latency hides under the
// previous tile's 640-FMA compute phase.
__device__ __forceinline__ void pipe_barrier() {
    __builtin_amdgcn_sched_barrier(0);
    asm volatile("s_waitcnt lgkmcnt(0)" ::: "memory");
    __builtin_amdgcn_sched_barrier(0);
    __builtin_amdgcn_s_barrier();
    __builtin_amdgcn_sched_barrier(0);
}

__global__ __launch_bounds__(256, 3) void k_gemm1(const float* __restrict__ x,
                                                  const float* __restrict__ W1,
                                                  float* __restrict__ sup1) {
    __shared__ float xs[2][128 * 36];   // [buf][row][k], pad 36 (16B aligned, 2-way banks)
    __shared__ float wsT[2][40 * 36];   // [buf][col][k]
    const int tid = threadIdx.x;
    const int colgrp = tid & 3;      // 4 groups x 10 cols
    const int rowid = tid >> 2;      // 0..63, rows rowid & rowid+64
    const int row0 = blockIdx.x * 128;
    const int kkx = tid & 31;        // k-offset within tile (constant per thread)
    const int rsub = tid >> 5;       // 0..7

    // 16 x-tile row offsets (int is safe: 99999*1433 < 2^31)
    int rowbase[16];
#pragma unroll
    for (int it = 0; it < 16; ++it) {
        int r = row0 + it * 8 + rsub;
        if (r >= N_NODES) r = N_NODES - 1;
        rowbase[it] = r * NFEAT;
    }
    // W-tile LDS scatter addresses (transpose [k][c] -> [c][k])
    int waddr[5];
#pragma unroll
    for (int it = 0; it < 5; ++it) {
        int flat = it * 256 + tid;
        int k = flat / 40, c = flat - k * 40;
        waddr[it] = c * 36 + k;
    }
    const int xaddr = rsub * 36 + kkx;   // + it*(8*36) per it

    float xr[16], wr[5];
    float acc[2][10];
#pragma unroll
    for (int j = 0; j < 2; ++j)
#pragma unroll
        for (int c = 0; c < 10; ++c) acc[j][c] = 0.f;

#define LOADT(t)                                                          \
    {                                                                     \
        const int k0_ = (t) * 32;                                         \
        const int gk_ = k0_ + kkx;                                        \
        const bool okx_ = gk_ < NFEAT;                                    \
        _Pragma("unroll")                                                 \
        for (int it = 0; it < 16; ++it)                                   \
            xr[it] = okx_ ? x[rowbase[it] + gk_] : 0.f;                   \
        _Pragma("unroll")                                                 \
        for (int it = 0; it < 5; ++it) {                                  \
            int idx_ = k0_ * NHID + it * 256 + tid;                       \
            wr[it] = (idx_ < NFEAT * NHID) ? W1[idx_] : 0.f;              \
        }                                                                 \
    }

#define WRITET(b)                                                         \
    {                                                                     \
        float* xb_ = xs[b];                                               \
        float* wb_ = wsT[b];                                              \
        _Pragma("unroll")                                                 \
        for (int it = 0; it < 16; ++it)                                   \
            xb_[it * (8 * 36) + xaddr] = xr[it];                          \
        _Pragma("unroll")                                                 \
        for (int it = 0; it < 5; ++it)                                    \
            wb_[waddr[it]] = wr[it];                                      \
    }

    LOADT(0);
    WRITET(0);          // compiler inserts the vmcnt wait on xr/wr here
    LOADT(1);           // tile 1 loads remain in flight across the barrier
    pipe_barrier();

    for (int t = 0; t < GTILE; ++t) {
        const int cur = t & 1;
        const float* xb = xs[cur];
        const float* wb = wsT[cur];
#pragma unroll
        for (int kk = 0; kk < 32; kk += 4) {
            float4 xv0 = *(const float4*)(xb + rowid * 36 + kk);
            float4 xv1 = *(const float4*)(xb + (rowid + 64) * 36 + kk);
#pragma unroll
            for (int c = 0; c < 10; ++c) {
                float4 wv = *(const float4*)(wb + (colgrp * 10 + c) * 36 + kk);
                acc[0][c] += xv0.x * wv.x + xv0.y * wv.y + xv0.z * wv.z + xv0.w * wv.w;
                acc[1][c] += xv1.x * wv.x + xv1.y * wv.y + xv1.z * wv.z + xv1.w * wv.w;
            }
        }
        if (t + 1 < GTILE) WRITET(cur ^ 1);   // tile t+1 regs -> other buffer
        if (t + 2 < GTILE) LOADT(t + 2);      // issue next loads; stay in flight
        pipe_barrier();                        // lgkmcnt(0) only — no vmcnt drain
    }
#undef LOADT
#undef WRITET

#pragma unroll
    for (int j = 0; j < 2; ++j) {
        int row = row0 + rowid + 64 * j;
        if (row < N_NODES) {
            float* dp = sup1 + (size_t)row * NHID + colgrp * 10;
#pragma unroll
            for (int c = 0; c < 10; ++c) dp[c] = acc[j][c];
        }
    }
}

// ---------------- agg1: h = relu(A @ sup1 + b1) * dropout ----------------
__global__ __launch_bounds__(256) void k_agg1(const float* __restrict__ sup1,
                                              const int* __restrict__ row_ptr,
                                              const int2* __restrict__ csr,
                                              const float* __restrict__ b1,
                                              const float* __restrict__ mask,
                                              float* __restrict__ h) {
    int wave = threadIdx.x >> 6;
    int lane = threadIdx.x & 63;
    int n = blockIdx.x * 4 + wave;
    if (n >= N_NODES) return;
    int start = row_ptr[n], end = row_ptr[n + 1];
    int half = lane >> 5, hl = lane & 31;   // 2 edges in flight
    float4 acc = make_float4(0.f, 0.f, 0.f, 0.f);
    for (int e = start + half; e < end; e += 2) {
        int2 p = csr[e];
        float w = __int_as_float(p.y);
        if (hl < 10) {
            float4 v = *(const float4*)(sup1 + (size_t)p.x * NHID + hl * 4);
            acc.x += w * v.x; acc.y += w * v.y; acc.z += w * v.z; acc.w += w * v.w;
        }
    }
    acc.x += __shfl_xor(acc.x, 32);
    acc.y += __shfl_xor(acc.y, 32);
    acc.z += __shfl_xor(acc.z, 32);
    acc.w += __shfl_xor(acc.w, 32);
    if (half == 0 && hl < 10) {
        float4 bb = *(const float4*)(b1 + hl * 4);
        const float* mp = mask + (size_t)n * NHID + hl * 4;
        float4 r;
        r.x = fmaxf(acc.x + bb.x, 0.f) * (mp[0] > 0.5f ? 2.f : 0.f);
        r.y = fmaxf(acc.y + bb.y, 0.f) * (mp[1] > 0.5f ? 2.f : 0.f);
        r.z = fmaxf(acc.z + bb.z, 0.f) * (mp[2] > 0.5f ? 2.f : 0.f);
        r.w = fmaxf(acc.w + bb.w, 0.f) * (mp[3] > 0.5f ? 2.f : 0.f);
        *(float4*)(h + (size_t)n * NHID + hl * 4) = r;
    }
}

// ---------------- GEMM2: sup2[N,7] = h[N,40] @ W2[40,7] ----------------
__global__ __launch_bounds__(256) void k_gemm2(const float* __restrict__ h,
                                               const float* __restrict__ W2,
                                               float* __restrict__ sup2) {
    __shared__ float hs[256 * 42];   // pad 42: float2-aligned, 2-way banks
    __shared__ float w2s[NHID * NCLASS];
    const int tid = threadIdx.x;
    const int n0 = blockIdx.x * 256;
    for (int i = tid; i < NHID * NCLASS; i += 256) w2s[i] = W2[i];
#pragma unroll
    for (int it = 0; it < 20; ++it) {     // 256 rows x 20 float2, coalesced
        int flat = it * 256 + tid;
        int r = flat / 20, q = flat - r * 20;
        int grow = n0 + r; if (grow >= N_NODES) grow = N_NODES - 1;
        float2 v = *(const float2*)(h + (size_t)grow * NHID + q * 2);
        *(float2*)(hs + r * 42 + q * 2) = v;
    }
    __syncthreads();
    int n = n0 + tid;
    float acc[NCLASS];
#pragma unroll
    for (int c = 0; c < NCLASS; ++c) acc[c] = 0.f;
#pragma unroll
    for (int k = 0; k < NHID; ++k) {
        float hv = hs[tid * 42 + k];
#pragma unroll
        for (int c = 0; c < NCLASS; ++c) acc[c] += hv * w2s[k * NCLASS + c];
    }
    if (n < N_NODES) {
        float* dp = sup2 + (size_t)n * NCLASS;
#pragma unroll
        for (int c = 0; c < NCLASS; ++c) dp[c] = acc[c];
    }
}

// ---------------- agg2 + bias + log_softmax ----------------
__global__ __launch_bounds__(256) void k_agg2(const float* __restrict__ sup2,
                                              const int* __restrict__ row_ptr,
                                              const int2* __restrict__ csr,
                                              const float* __restrict__ b2,
                                              float* __restrict__ out) {
    int wave = threadIdx.x >> 6;
    int lane = threadIdx.x & 63;
    int n = blockIdx.x * 4 + wave;
    if (n >= N_NODES) return;
    int start = row_ptr[n], end = row_ptr[n + 1];
    int g = lane >> 3, f = lane & 7;    // 8 edge-groups x 8 feature lanes
    float acc = 0.f;
    for (int base = start; base < end; base += 8) {
        int e = base + g;
        if (e < end) {
            int2 p = csr[e];
            if (f < NCLASS) acc += __int_as_float(p.y) * sup2[(size_t)p.x * NCLASS + f];
        }
    }
    acc += __shfl_xor(acc, 8);
    acc += __shfl_xor(acc, 16);
    acc += __shfl_xor(acc, 32);
    float v = (f < NCLASS) ? acc + b2[f] : -INFINITY;
    float m = v;
    m = fmaxf(m, __shfl_xor(m, 1));
    m = fmaxf(m, __shfl_xor(m, 2));
    m = fmaxf(m, __shfl_xor(m, 4));
    float ex = expf(v - m);             // f==7 -> exp(-inf)=0
    float s = ex;
    s += __shfl_xor(s, 1);
    s += __shfl_xor(s, 2);
    s += __shfl_xor(s, 4);
    if (g == 0 && f < NCLASS) out[(size_t)n * NCLASS + f] = v - m - logf(s);
}

extern "C" void kernel_launch(void* const* d_in, const int* in_sizes, int n_in,
                              void* d_out, int out_size, void* d_ws, size_t ws_size,
                              hipStream_t stream) {
    const float* x    = (const float*)d_in[0];
    const int*   src  = (const int*)d_in[1];
    const int*   dst  = (const int*)d_in[2];
    const float* ew   = (const float*)d_in[3];
    const float* W1   = (const float*)d_in[4];
    const float* b1   = (const float*)d_in[5];
    const float* W2   = (const float*)d_in[6];
    const float* b2   = (const float*)d_in[7];
    const float* mask = (const float*)d_in[8];
    float* out = (float*)d_out;

    char* ws = (char*)d_ws;
    float* sup1   = (float*)(ws + 0);          // 16,000,000 B
    float* h      = (float*)(ws + 16000000);   // 16,000,000 B
    float* sup2   = (float*)(ws + 32000000);   //  2,800,000 B
    int* row_ptr  = (int*)(ws + 34800000);     //    400,004 B
    int* cursor   = (int*)(ws + 35200016);     //    400,000 B
    int* deg      = (int*)(ws + 35600016);     //    400,000 B
    int* csum     = (int*)(ws + 36000016);     //      1,564 B
    int2* csr     = (int2*)(ws + 36001584);    // 25,600,000 B  (end ~61.6 MB)

    hipMemsetAsync(deg, 0, N_NODES * sizeof(int), stream);
    k_hist   <<<(N_EDGES + 255) / 256, 256, 0, stream>>>(dst, deg);
    k_scan1  <<<NCHUNK, 256, 0, stream>>>(deg, csum);
    k_scan2  <<<1, 512, 0, stream>>>(csum);
    k_scan3  <<<NCHUNK, 256, 0, stream>>>(deg, csum, row_ptr, cursor);
    k_scatter<<<(N_EDGES + 255) / 256, 256, 0, stream>>>(src, dst, ew, cursor, csr);
    k_gemm1  <<<(N_NODES + 127) / 128, 256, 0, stream>>>(x, W1, sup1);
    k_agg1   <<<N_NODES / 4, 256, 0, stream>>>(sup1, row_ptr, csr, b1, mask, h);
    k_gemm2  <<<(N_NODES + 255) / 256, 256, 0, stream>>>(h, W2, sup2);
    k_agg2   <<<N_NODES / 4, 256, 0, stream>>>(sup2, row_ptr, csr, b2, out);
}

// Round 2
// 2494.952 us; speedup vs baseline: 6.6475x; 6.6475x over previous
//
#include <hip/hip_runtime.h>
#include <math.h>

#define N_NODES 100000
#define N_EDGES 3200000
#define NFEAT   1433
#define NHID    40
#define NCLASS  7
#define NCHUNK  391   // ceil(100000/256)
#define GTILE   45    // ceil(1433/32)

// ---------------- CSR build ----------------
__global__ __launch_bounds__(256) void k_hist(const int* __restrict__ dst, int* __restrict__ deg) {
    int e = blockIdx.x * 256 + threadIdx.x;
    if (e < N_EDGES) atomicAdd(&deg[dst[e]], 1);
}

__global__ __launch_bounds__(256) void k_scan1(const int* __restrict__ deg, int* __restrict__ csum) {
    __shared__ int s[256];
    int tid = threadIdx.x;
    int n = blockIdx.x * 256 + tid;
    int v = (n < N_NODES) ? deg[n] : 0;
    s[tid] = v; __syncthreads();
    for (int off = 128; off > 0; off >>= 1) {
        if (tid < off) s[tid] += s[tid + off];
        __syncthreads();
    }
    if (tid == 0) csum[blockIdx.x] = s[0];
}

__global__ __launch_bounds__(512) void k_scan2(int* __restrict__ csum) {
    __shared__ int s[512];
    int tid = threadIdx.x;
    int v = (tid < NCHUNK) ? csum[tid] : 0;
    s[tid] = v; __syncthreads();
    for (int off = 1; off < 512; off <<= 1) {
        int t = (tid >= off) ? s[tid - off] : 0;
        __syncthreads();
        s[tid] += t;
        __syncthreads();
    }
    if (tid < NCHUNK) csum[tid] = s[tid] - v;  // exclusive
}

__global__ __launch_bounds__(256) void k_scan3(const int* __restrict__ deg, const int* __restrict__ csum,
                                               int* __restrict__ row_ptr, int* __restrict__ cursor) {
    __shared__ int s[256];
    int tid = threadIdx.x;
    int n = blockIdx.x * 256 + tid;
    int v = (n < N_NODES) ? deg[n] : 0;
    s[tid] = v; __syncthreads();
    for (int off = 1; off < 256; off <<= 1) {
        int t = (tid >= off) ? s[tid - off] : 0;
        __syncthreads();
        s[tid] += t;
        __syncthreads();
    }
    int excl = s[tid] - v + csum[blockIdx.x];
    if (n < N_NODES) { row_ptr[n] = excl; cursor[n] = excl; }
    if (n == 0) row_ptr[N_NODES] = N_EDGES;
}

__global__ __launch_bounds__(256) void k_scatter(const int* __restrict__ src, const int* __restrict__ dst,
                                                 const float* __restrict__ ew, int* __restrict__ cursor,
                                                 int2* __restrict__ csr) {
    int e = blockIdx.x * 256 + threadIdx.x;
    if (e < N_EDGES) {
        int d = dst[e];
        int pos = atomicAdd(&cursor[d], 1);
        int2 p; p.x = src[e]; p.y = __float_as_int(ew[e]);
        csr[pos] = p;
    }
}

// ---------------- GEMM1: sup1[N,40] = x[N,1433] @ W1[1433,40] ----------------
// 2-phase pipeline (T3-minimum): x staged by global_load_lds (zero staging
// VGPRs) into a linear stride-32 tile with XOR-swizzled source/read addresses
// (bank-conflict-free without padding); W reg-staged (5 regs) into a padded
// transposed tile. Double buffers are STATICALLY-NAMED arrays (t-loop
// unrolled x2) so alias analysis keeps in-flight loads (next buf) from
// forcing a vmcnt drain before the compute ds_reads (current buf).

__device__ __forceinline__ void gl_lds4(const float* g, float* l) {
    __builtin_amdgcn_global_load_lds(
        (const __attribute__((address_space(1))) void*)g,
        (__attribute__((address_space(3))) void*)l, 4, 0, 0);
}

__global__ __launch_bounds__(256) void k_gemm1(const float* __restrict__ x,
                                               const float* __restrict__ W1,
                                               float* __restrict__ sup1) {
    __shared__ float xsA[128 * 32];   // [r][klin], linear (global_load_lds dest)
    __shared__ float xsB[128 * 32];
    __shared__ float wsA[40 * 36];    // [c][k], pad 36 (reg-staged, broadcast reads)
    __shared__ float wsB[40 * 36];

    const int tid = threadIdx.x;
    const int lane = tid & 63;
    const int wave = tid >> 6;
    const int colgrp = tid & 3;       // 4 groups x 10 cols
    const int rowid = tid >> 2;       // 0..63, rows rowid & rowid+64
    const int row0 = blockIdx.x * 128;
    const int xorv = (rowid & 7) << 2;

    // staging geometry: slot s = wave*1024 + i*64 + lane; r = s>>5, klin = s&31
    const int r_lane = wave * 32 + (lane >> 5);
    const int klin = lane & 31;
    int klx[4];
#pragma unroll
    for (int m = 0; m < 4; ++m)
        klx[m] = klin ^ ((((lane >> 5) + 2 * m) & 7) << 2);

    // W-tile LDS scatter addresses (transpose [k][c] -> [c][k])
    int waddr[5];
#pragma unroll
    for (int it = 0; it < 5; ++it) {
        int flat = it * 256 + tid;
        int k = flat / 40, c = flat - k * 40;
        waddr[it] = c * 36 + k;
    }

    float wr[5];
    float acc[2][10];
#pragma unroll
    for (int j = 0; j < 2; ++j)
#pragma unroll
        for (int c = 0; c < 10; ++c) acc[j][c] = 0.f;

#define STAGE_X(t, XB)                                                    \
    {                                                                     \
        const int k0_ = (t) * 32;                                         \
        _Pragma("unroll")                                                 \
        for (int i = 0; i < 16; ++i) {                                    \
            int row_ = row0 + r_lane + 2 * i;                             \
            if (row_ > N_NODES - 1) row_ = N_NODES - 1;                   \
            int gk_ = k0_ + klx[i & 3];                                   \
            if (gk_ > NFEAT - 1) gk_ = NFEAT - 1;                         \
            gl_lds4(x + (size_t)row_ * NFEAT + gk_,                       \
                    (XB) + wave * 1024 + i * 64);                         \
        }                                                                 \
    }

#define LOADW(t)                                                          \
    {                                                                     \
        const int base_ = (t) * 32 * NHID + tid;                          \
        _Pragma("unroll")                                                 \
        for (int it = 0; it < 5; ++it) {                                  \
            int idx_ = base_ + it * 256;                                  \
            wr[it] = (idx_ < NFEAT * NHID) ? W1[idx_] : 0.f;              \
        }                                                                 \
    }

#define WRITEW(WB)                                                        \
    {                                                                     \
        _Pragma("unroll")                                                 \
        for (int it = 0; it < 5; ++it) (WB)[waddr[it]] = wr[it];          \
    }

#define COMPUTE(XB, WB)                                                   \
    {                                                                     \
        const float* xb_ = (XB) + rowid * 32;                             \
        const float* wb_ = (WB) + colgrp * 360;                           \
        _Pragma("unroll")                                                 \
        for (int kk = 0; kk < 32; kk += 4) {                              \
            int xo_ = kk ^ xorv;                                          \
            float4 xv0 = *(const float4*)(xb_ + xo_);                     \
            float4 xv1 = *(const float4*)(xb_ + xo_ + 2048);              \
            _Pragma("unroll")                                             \
            for (int c = 0; c < 10; ++c) {                                \
                float4 wv = *(const float4*)(wb_ + c * 36 + kk);          \
                acc[0][c] += xv0.x * wv.x + xv0.y * wv.y +                \
                             xv0.z * wv.z + xv0.w * wv.w;                 \
                acc[1][c] += xv1.x * wv.x + xv1.y * wv.y +                \
                             xv1.z * wv.z + xv1.w * wv.w;                 \
            }                                                             \
        }                                                                 \
    }

#define ITER(t, CX, CW, NX, NW)                                           \
    {                                                                     \
        LOADW((t) + 1);                                                   \
        STAGE_X((t) + 1, NX);                                             \
        __builtin_amdgcn_sched_barrier(0);                                \
        COMPUTE(CX, CW);                                                  \
        WRITEW(NW);                                                       \
        __syncthreads();                                                  \
    }

    // prologue: stage tile 0, full drain
    LOADW(0);
    STAGE_X(0, xsA);
    WRITEW(wsA);
    __syncthreads();

    // main loop: tiles 0..43 (pairs, static buffer names); tile 44 in tail
    for (int t = 0; t < GTILE - 1; t += 2) {
        ITER(t,     xsA, wsA, xsB, wsB);
        ITER(t + 1, xsB, wsB, xsA, wsA);
    }
    COMPUTE(xsA, wsA);   // tile 44 (44 & 1 == 0 -> A buffers)

#undef STAGE_X
#undef LOADW
#undef WRITEW
#undef COMPUTE
#undef ITER

#pragma unroll
    for (int j = 0; j < 2; ++j) {
        int row = row0 + rowid + 64 * j;
        if (row < N_NODES) {
            float* dp = sup1 + (size_t)row * NHID + colgrp * 10;
#pragma unroll
            for (int c = 0; c < 10; ++c) dp[c] = acc[j][c];
        }
    }
}

// ---------------- agg1: h = relu(A @ sup1 + b1) * dropout ----------------
__global__ __launch_bounds__(256) void k_agg1(const float* __restrict__ sup1,
                                              const int* __restrict__ row_ptr,
                                              const int2* __restrict__ csr,
                                              const float* __restrict__ b1,
                                              const float* __restrict__ mask,
                                              float* __restrict__ h) {
    int wave = threadIdx.x >> 6;
    int lane = threadIdx.x & 63;
    int n = blockIdx.x * 4 + wave;
    if (n >= N_NODES) return;
    int start = row_ptr[n], end = row_ptr[n + 1];
    int half = lane >> 5, hl = lane & 31;   // 2 edges in flight
    float4 acc = make_float4(0.f, 0.f, 0.f, 0.f);
    for (int e = start + half; e < end; e += 2) {
        int2 p = csr[e];
        float w = __int_as_float(p.y);
        if (hl < 10) {
            float4 v = *(const float4*)(sup1 + (size_t)p.x * NHID + hl * 4);
            acc.x += w * v.x; acc.y += w * v.y; acc.z += w * v.z; acc.w += w * v.w;
        }
    }
    acc.x += __shfl_xor(acc.x, 32);
    acc.y += __shfl_xor(acc.y, 32);
    acc.z += __shfl_xor(acc.z, 32);
    acc.w += __shfl_xor(acc.w, 32);
    if (half == 0 && hl < 10) {
        float4 bb = *(const float4*)(b1 + hl * 4);
        const float* mp = mask + (size_t)n * NHID + hl * 4;
        float4 r;
        r.x = fmaxf(acc.x + bb.x, 0.f) * (mp[0] > 0.5f ? 2.f : 0.f);
        r.y = fmaxf(acc.y + bb.y, 0.f) * (mp[1] > 0.5f ? 2.f : 0.f);
        r.z = fmaxf(acc.z + bb.z, 0.f) * (mp[2] > 0.5f ? 2.f : 0.f);
        r.w = fmaxf(acc.w + bb.w, 0.f) * (mp[3] > 0.5f ? 2.f : 0.f);
        *(float4*)(h + (size_t)n * NHID + hl * 4) = r;
    }
}

// ---------------- GEMM2: sup2[N,7] = h[N,40] @ W2[40,7] ----------------
__global__ __launch_bounds__(256) void k_gemm2(const float* __restrict__ h,
                                               const float* __restrict__ W2,
                                               float* __restrict__ sup2) {
    __shared__ float hs[256 * 42];   // pad 42: float2-aligned, 2-way banks
    __shared__ float w2s[NHID * NCLASS];
    const int tid = threadIdx.x;
    const int n0 = blockIdx.x * 256;
    for (int i = tid; i < NHID * NCLASS; i += 256) w2s[i] = W2[i];
#pragma unroll
    for (int it = 0; it < 20; ++it) {     // 256 rows x 20 float2, coalesced
        int flat = it * 256 + tid;
        int r = flat / 20, q = flat - r * 20;
        int grow = n0 + r; if (grow >= N_NODES) grow = N_NODES - 1;
        float2 v = *(const float2*)(h + (size_t)grow * NHID + q * 2);
        *(float2*)(hs + r * 42 + q * 2) = v;
    }
    __syncthreads();
    int n = n0 + tid;
    float acc[NCLASS];
#pragma unroll
    for (int c = 0; c < NCLASS; ++c) acc[c] = 0.f;
#pragma unroll
    for (int k = 0; k < NHID; ++k) {
        float hv = hs[tid * 42 + k];
#pragma unroll
        for (int c = 0; c < NCLASS; ++c) acc[c] += hv * w2s[k * NCLASS + c];
    }
    if (n < N_NODES) {
        float* dp = sup2 + (size_t)n * NCLASS;
#pragma unroll
        for (int c = 0; c < NCLASS; ++c) dp[c] = acc[c];
    }
}

// ---------------- agg2 + bias + log_softmax ----------------
__global__ __launch_bounds__(256) void k_agg2(const float* __restrict__ sup2,
                                              const int* __restrict__ row_ptr,
                                              const int2* __restrict__ csr,
                                              const float* __restrict__ b2,
                                              float* __restrict__ out) {
    int wave = threadIdx.x >> 6;
    int lane = threadIdx.x & 63;
    int n = blockIdx.x * 4 + wave;
    if (n >= N_NODES) return;
    int start = row_ptr[n], end = row_ptr[n + 1];
    int g = lane >> 3, f = lane & 7;    // 8 edge-groups x 8 feature lanes
    float acc = 0.f;
    for (int base = start; base < end; base += 8) {
        int e = base + g;
        if (e < end) {
            int2 p = csr[e];
            if (f < NCLASS) acc += __int_as_float(p.y) * sup2[(size_t)p.x * NCLASS + f];
        }
    }
    acc += __shfl_xor(acc, 8);
    acc += __shfl_xor(acc, 16);
    acc += __shfl_xor(acc, 32);
    float v = (f < NCLASS) ? acc + b2[f] : -INFINITY;
    float m = v;
    m = fmaxf(m, __shfl_xor(m, 1));
    m = fmaxf(m, __shfl_xor(m, 2));
    m = fmaxf(m, __shfl_xor(m, 4));
    float ex = expf(v - m);             // f==7 -> exp(-inf)=0
    float s = ex;
    s += __shfl_xor(s, 1);
    s += __shfl_xor(s, 2);
    s += __shfl_xor(s, 4);
    if (g == 0 && f < NCLASS) out[(size_t)n * NCLASS + f] = v - m - logf(s);
}

extern "C" void kernel_launch(void* const* d_in, const int* in_sizes, int n_in,
                              void* d_out, int out_size, void* d_ws, size_t ws_size,
                              hipStream_t stream) {
    const float* x    = (const float*)d_in[0];
    const int*   src  = (const int*)d_in[1];
    const int*   dst  = (const int*)d_in[2];
    const float* ew   = (const float*)d_in[3];
    const float* W1   = (const float*)d_in[4];
    const float* b1   = (const float*)d_in[5];
    const float* W2   = (const float*)d_in[6];
    const float* b2   = (const float*)d_in[7];
    const float* mask = (const float*)d_in[8];
    float* out = (float*)d_out;

    char* ws = (char*)d_ws;
    float* sup1   = (float*)(ws + 0);          // 16,000,000 B
    float* h      = (float*)(ws + 16000000);   // 16,000,000 B
    float* sup2   = (float*)(ws + 32000000);   //  2,800,000 B
    int* row_ptr  = (int*)(ws + 34800000);     //    400,004 B
    int* cursor   = (int*)(ws + 35200016);     //    400,000 B
    int* deg      = (int*)(ws + 35600016);     //    400,000 B
    int* csum     = (int*)(ws + 36000016);     //      1,564 B
    int2* csr     = (int2*)(ws + 36001584);    // 25,600,000 B  (end ~61.6 MB)

    hipMemsetAsync(deg, 0, N_NODES * sizeof(int), stream);
    k_hist   <<<(N_EDGES + 255) / 256, 256, 0, stream>>>(dst, deg);
    k_scan1  <<<NCHUNK, 256, 0, stream>>>(deg, csum);
    k_scan2  <<<1, 512, 0, stream>>>(csum);
    k_scan3  <<<NCHUNK, 256, 0, stream>>>(deg, csum, row_ptr, cursor);
    k_scatter<<<(N_EDGES + 255) / 256, 256, 0, stream>>>(src, dst, ew, cursor, csr);
    k_gemm1  <<<(N_NODES + 127) / 128, 256, 0, stream>>>(x, W1, sup1);
    k_agg1   <<<N_NODES / 4, 256, 0, stream>>>(sup1, row_ptr, csr, b1, mask, h);
    k_gemm2  <<<(N_NODES + 255) / 256, 256, 0, stream>>>(h, W2, sup2);
    k_agg2   <<<N_NODES / 4, 256, 0, stream>>>(sup2, row_ptr, csr, b2, out);
}